// Round 3
// baseline (279.583 us; speedup 1.0000x reference)
//
#include <hip/hip_runtime.h>

// out[h1,w1,c1,h2,w2,c2] =
//   gamma^(|h1-h2|+|w1-w2|+|c1-c2|) * (1 + spec_pe[c1,c2]*mean[h1,w1,c1]) * decay[c1]
// mean[h1,w1,c1] = Sh(h1)*Sw(w1)*Sc(c1)/8192, S(t,N) = 19 - 9*(0.9^t + 0.9^{N-1-t})
// H=W=32, C=8. Output 256 MiB fp32 — pure write-bound generator.
//
// R2: fill-kernel-shaped. No LDS, no barriers, closed-form factors in registers,
// 2048 blocks (exactly 8/CU, fully resident, single shot), 32 dwordx4 stores per
// thread back-to-back. R0/R1 both plateaued at ~93 us of non-fill time; this
// tests (and fixes, if true) the "structural store-stream" hypothesis.

constexpr float L2G = -0.15200309344504997f;  // log2(0.9)

__global__ __launch_bounds__(256, 8) void manhattan_relpos_fill(
    const float* __restrict__ decay,    // 8 elems
    const float* __restrict__ spec_pe,  // 64 elems
    float* __restrict__ out)            // 67,108,864 floats
{
    const int tid  = threadIdx.x;
    const int lane = tid & 63;
    const int wave = tid >> 6;            // 0..3
    const int blk  = blockIdx.x;          // 0..2047

    // float4-index bits: 0=c2half, 1-5=w2, 6-10=h2(i), 11-12=c1lo(wave),
    //                    13=c1hi(blk0), 14-18=w1, 19-23=h1
    const int half = lane & 1;
    const int w2   = lane >> 1;
    const int c1   = wave | ((blk & 1) << 2);
    const int w1   = (blk >> 1) & 31;
    const int h1   = blk >> 6;

    // closed-form axis sums of gamma^|t-j|
    const float Sh1 = 19.0f - 9.0f * (exp2f((float)h1 * L2G) + exp2f((float)(31 - h1) * L2G));
    const float Sw1 = 19.0f - 9.0f * (exp2f((float)w1 * L2G) + exp2f((float)(31 - w1) * L2G));
    const float Sc1 = 19.0f - 9.0f * (exp2f((float)c1 * L2G) + exp2f((float)(7  - c1) * L2G));
    const float m   = Sh1 * Sw1 * Sc1 * (1.0f / 8192.0f);

    const float pw  = exp2f(fabsf((float)(w1 - w2)) * L2G);
    const float dec = decay[c1];

    float K[4];
    #pragma unroll
    for (int j = 0; j < 4; ++j) {
        const int c2   = (half << 2) + j;
        const float pc = exp2f(fabsf((float)(c1 - c2)) * L2G);
        const float sp = spec_pe[(c1 << 3) + c2];
        K[j] = pw * pc * dec * fmaf(sp, m, 1.0f);
    }

    float ph[32];
    #pragma unroll
    for (int i = 0; i < 32; ++i)
        ph[i] = exp2f(fabsf((float)(h1 - i)) * L2G);

    float4* outp = reinterpret_cast<float4*>(out)
                 + ((size_t)blk << 13) + (wave << 11) + lane;
    #pragma unroll
    for (int i = 0; i < 32; ++i) {
        float4 v;
        v.x = ph[i] * K[0];
        v.y = ph[i] * K[1];
        v.z = ph[i] * K[2];
        v.w = ph[i] * K[3];
        outp[i << 6] = v;   // wave writes 1 KiB contiguous per store
    }
}

extern "C" void kernel_launch(void* const* d_in, const int* in_sizes, int n_in,
                              void* d_out, int out_size, void* d_ws, size_t ws_size,
                              hipStream_t stream) {
    // d_in[0] = x (values unused by the math)
    const float* decay   = (const float*)d_in[1];
    const float* spec_pe = (const float*)d_in[2];
    float* out = (float*)d_out;

    dim3 grid(2048), block(256);
    manhattan_relpos_fill<<<grid, block, 0, stream>>>(decay, spec_pe, out);
}